// Round 5
// baseline (1444.727 us; speedup 1.0000x reference)
//
#include <hip/hip_runtime.h>

// out[b,i,j,:,:] = exp6(M), M[k,l] = sum_d (x[b,j,d]-x[b,i,d]) * A[b,j,d,k,l]
// Block = (b,j), all 512 i's in 2 macro-passes of 256. Per macro-pass the
// 128 KB A-panel streams global->LDS(bf16 chunks) once -> panel fetched 2x
// per block total (was 5x: Tjrow + 4 passes). Tjrow phase deleted by folding
// (x_j - x_i) into the MFMA A-operand (verified R2/R3, same absmax).
// Epilogue: 4 sub-passes of 64 i, 4 threads/i Taylor (keeps VGPR <= 128 for
// the 4-blocks/CU occupancy cliff; LDS 25.4 KB allows 6).

typedef short short8 __attribute__((ext_vector_type(8)));
typedef float f32x4 __attribute__((ext_vector_type(4)));

constexpr int S = 512, D = 512, MM = 64;
constexpr int TS_STRIDE = 65;   // Taylor phase (conflict-free-ish b32 reads)
constexpr int RES_STRIDE = 68;  // write-out phase (16B-aligned rows)

// pack two f32 -> two bf16 (round-half-up) in one v_perm
__device__ inline unsigned pack2(float lo, float hi) {
  unsigned a = __float_as_uint(lo) + 0x8000u;
  unsigned b = __float_as_uint(hi) + 0x8000u;
  return __builtin_amdgcn_perm(b, a, 0x07060302);  // [a.b2,a.b3,b.b2,b.b3]
}

__global__ __launch_bounds__(256, 4)
void pt_kernel(const float* __restrict__ x, const float* __restrict__ A,
               float* __restrict__ out) {
  const int bid = blockIdx.x;
  const int b = bid >> 9;          // 512 j per b
  const int j = bid & (S - 1);
  const int t = threadIdx.x;
  const int w = t >> 6;
  const int L = t & 63;
  const int quad = L >> 4;
  const int l15 = L & 15;

  __shared__ short8 Bf[8 * 64];               // 8 KB   (kk*4+mt)*64+L, lane-linear
  __shared__ float TsRes[64 * RES_STRIDE];    // 17.4 KB union: Ts then Res (per sub-pass)

  const float* xb = x + (size_t)b * S * D;
  const float* Ab = A + (size_t)(b * S + j) * (size_t)(D * MM);
  const float* xjr = xb + (size_t)j * D;      // x[b,j,:] (2 KB, L1-hot)

  const int mcol = w * 16 + l15;

  for (int mp = 0; mp < 2; ++mp) {
    // wave w owns rows [mp*256 + w*64, +64): 4 i-tiles of 16
    f32x4 acc[4][4];
#pragma unroll
    for (int it = 0; it < 4; ++it)
#pragma unroll
      for (int mt = 0; mt < 4; ++mt) acc[it][mt] = (f32x4){0.f, 0.f, 0.f, 0.f};

    const float* xrow[4];
#pragma unroll
    for (int it = 0; it < 4; ++it)
      xrow[it] = xb + (size_t)(mp * 256 + w * 64 + it * 16 + l15) * D;

    for (int d0 = 0; d0 < D; d0 += 64) {
      __syncthreads();  // previous chunk's Bf reads complete
      // ---- stage B fragments: wave w owns m-tile w, kk = 0,1 ----
#pragma unroll
      for (int kk = 0; kk < 2; ++kk) {
        const float* ap = Ab + (size_t)(d0 + kk * 32 + quad * 8) * MM + mcol;
        const float e0 = ap[0 * MM], e1 = ap[1 * MM], e2 = ap[2 * MM], e3 = ap[3 * MM];
        const float e4 = ap[4 * MM], e5 = ap[5 * MM], e6 = ap[6 * MM], e7 = ap[7 * MM];
        union { unsigned u[4]; short8 s; } bf;
        bf.u[0] = pack2(e0, e1); bf.u[1] = pack2(e2, e3);
        bf.u[2] = pack2(e4, e5); bf.u[3] = pack2(e6, e7);
        Bf[(kk * 4 + w) * 64 + L] = bf.s;   // ds_write_b128, lane-linear
      }
      __syncthreads();
      // ---- compute: A-op = bf16(x_j - x_i); 2 kk x 4 i-tiles x 4 m-tiles ----
#pragma unroll
      for (int kk = 0; kk < 2; ++kk) {
        short8 bfr[4];
#pragma unroll
        for (int mt = 0; mt < 4; ++mt) bfr[mt] = Bf[(kk * 4 + mt) * 64 + L];
        const float* xjp = xjr + d0 + kk * 32 + quad * 8;   // broadcast within quad
        const float4 j0 = *(const float4*)xjp;
        const float4 j1 = *(const float4*)(xjp + 4);
#pragma unroll
        for (int it = 0; it < 4; ++it) {
          const float* xp = xrow[it] + d0 + kk * 32 + quad * 8;
          const float4 v0 = *(const float4*)xp;
          const float4 v1 = *(const float4*)(xp + 4);
          union { unsigned u[4]; short8 s; } af;
          af.u[0] = pack2(j0.x - v0.x, j0.y - v0.y);
          af.u[1] = pack2(j0.z - v0.z, j0.w - v0.w);
          af.u[2] = pack2(j1.x - v1.x, j1.y - v1.y);
          af.u[3] = pack2(j1.z - v1.z, j1.w - v1.w);
#pragma unroll
          for (int mt = 0; mt < 4; ++mt)
            acc[it][mt] = __builtin_amdgcn_mfma_f32_16x16x32_bf16(af.s, bfr[mt], acc[it][mt], 0, 0, 0);
        }
      }
    }

    // ---- epilogue: 4 sub-passes of 64 i (h = i-tile index) ----
#pragma unroll 1
    for (int h = 0; h < 4; ++h) {
      __syncthreads();  // previous sub-pass's Res reads (or last chunk's Bf reads) done
      // park acc[h]: local island iL = w*16 + quad*4 + r; global i = mp*256 + w*64 + h*16 + (quad*4+r)
#pragma unroll
      for (int mt = 0; mt < 4; ++mt)
#pragma unroll
        for (int r = 0; r < 4; ++r)
          TsRes[(w * 16 + quad * 4 + r) * TS_STRIDE + mt * 16 + l15] = acc[h][mt][r];
      __syncthreads();

      {
        const int i_loc = t >> 2;       // 4 threads per i (0..63)
        const int r0 = (t & 3) * 2;     // 2 rows each

        float Mi[8][8];
#pragma unroll
        for (int k = 0; k < 8; ++k)
#pragma unroll
          for (int l = 0; l < 8; ++l)
            Mi[k][l] = TsRes[i_loc * TS_STRIDE + k * 8 + l];  // M directly (no Tjrow)
        __syncthreads();  // all Ts reads done; TsRes becomes Res

        float Mp[2][8], res[2][8];
#pragma unroll
        for (int r = 0; r < 2; ++r)
#pragma unroll
          for (int c = 0; c < 8; ++c) {
            const float v = Mi[r0 + r][c];
            Mp[r][c] = v;
            res[r][c] = v + ((r0 + r) == c ? 1.0f : 0.0f);
          }

        const float invn[5] = {0.5f, 1.0f / 3.0f, 0.25f, 0.2f, 1.0f / 6.0f};
#pragma unroll
        for (int n = 0; n < 5; ++n) {
          float np[2][8];
#pragma unroll
          for (int r = 0; r < 2; ++r)
#pragma unroll
            for (int c = 0; c < 8; ++c) {
              float sum = 0.f;
#pragma unroll
              for (int k = 0; k < 8; ++k) sum += Mp[r][k] * Mi[k][c];
              np[r][c] = sum * invn[n];
            }
#pragma unroll
          for (int r = 0; r < 2; ++r)
#pragma unroll
            for (int c = 0; c < 8; ++c) {
              Mp[r][c] = np[r][c];
              res[r][c] += np[r][c];
            }
        }

        // stage result rows in LDS (stride 68: 16B-aligned rows)
#pragma unroll
        for (int r = 0; r < 2; ++r) {
          f32x4 lo = {res[r][0], res[r][1], res[r][2], res[r][3]};
          f32x4 hi = {res[r][4], res[r][5], res[r][6], res[r][7]};
          *(f32x4*)&TsRes[i_loc * RES_STRIDE + (r0 + r) * 8] = lo;
          *(f32x4*)&TsRes[i_loc * RES_STRIDE + (r0 + r) * 8 + 4] = hi;
        }
      }
      __syncthreads();

      // ---- store: 16 consecutive lanes cover one 256-B (i,j) island ----
      {
        const int part = t & 15;
        const int il = t >> 4;  // 0..15
#pragma unroll
        for (int step = 0; step < 4; ++step) {
          const int iL = step * 16 + il;                            // local island 0..63
          const int i = mp * 256 + (iL >> 4) * 64 + h * 16 + (iL & 15);
          const f32x4 v = *(const f32x4*)&TsRes[iL * RES_STRIDE + part * 4];
          *(f32x4*)(out + (((size_t)(b * S + i)) * S + j) * MM + part * 4) = v;
        }
      }
    }
  }
}

extern "C" void kernel_launch(void* const* d_in, const int* in_sizes, int n_in,
                              void* d_out, int out_size, void* d_ws, size_t ws_size,
                              hipStream_t stream) {
  const float* x = (const float*)d_in[0];
  const float* A = (const float*)d_in[1];
  float* out = (float*)d_out;
  const int B = in_sizes[0] / (S * D);  // 4
  pt_kernel<<<dim3(B * S), dim3(256), 0, stream>>>(x, A, out);
}

// Round 6
// 801.936 us; speedup vs baseline: 1.8015x; 1.8015x over previous
//
#include <hip/hip_runtime.h>

// out[b,i,j,:,:] = exp6(M), M[k,l] = sum_d (x[b,j,d]-x[b,i,d]) * A[b,j,d,k,l]
// Block = (b,j). MFMA phase: 2 macro-passes of 256 i (wave w owns i-tiles
// {4*it+w}, acc[4][4]) -> the 128 KB A-panel streams from memory 2x per
// block (R4 was 5x: Tjrow + 4 passes). Tjrow deleted via the fold
// (verified R2/R3/R5: absmax identical).
// Epilogue: EXACTLY R4's structure (the only one that holds WRITE_SIZE at
// the 786 MB floor -- every 64-i sub-pass variant blew it to 3.3-3.7 GB):
// two 128-i passes per macro-pass, park->2-thread/i Taylor->LDS res stage->
// 8-step full-line stores of 128 consecutive i.

typedef short short8 __attribute__((ext_vector_type(8)));
typedef float f32x4 __attribute__((ext_vector_type(4)));

constexpr int S = 512, D = 512, MM = 64;
constexpr int TS_STRIDE = 65;   // Taylor phase (conflict-free b32 reads)
constexpr int RES_STRIDE = 68;  // write-out phase (16B-aligned rows)

// pack two f32 -> two bf16 (round-half-up) in one v_perm
__device__ inline unsigned pack2(float lo, float hi) {
  unsigned a = __float_as_uint(lo) + 0x8000u;
  unsigned b = __float_as_uint(hi) + 0x8000u;
  return __builtin_amdgcn_perm(b, a, 0x07060302);  // [a.b2,a.b3,b.b2,b.b3]
}

__global__ __launch_bounds__(256, 3)
void pt_kernel(const float* __restrict__ x, const float* __restrict__ A,
               float* __restrict__ out) {
  const int bid = blockIdx.x;
  const int b = bid >> 9;          // 512 j per b
  const int j = bid & (S - 1);
  const int t = threadIdx.x;
  const int w = t >> 6;
  const int L = t & 63;
  const int quad = L >> 4;
  const int l15 = L & 15;

  __shared__ short8 Bf[8 * 64];                // 8 KB   (kk*4+mt)*64+L, lane-linear
  __shared__ float TsRes[128 * RES_STRIDE];    // 34.8 KB union: Ts then Res

  const float* xb = x + (size_t)b * S * D;
  const float* Ab = A + (size_t)(b * S + j) * (size_t)(D * MM);
  const float* xjr = xb + (size_t)j * D;       // x[b,j,:] (2 KB, L1-hot)

  const int mcol = w * 16 + l15;

  for (int mp = 0; mp < 2; ++mp) {
    // wave w owns i-tiles {4*it + w}: global i = mp*256 + (it*4+w)*16 + row
    f32x4 acc[4][4];
#pragma unroll
    for (int it = 0; it < 4; ++it)
#pragma unroll
      for (int mt = 0; mt < 4; ++mt) acc[it][mt] = (f32x4){0.f, 0.f, 0.f, 0.f};

    const float* xrow[4];
#pragma unroll
    for (int it = 0; it < 4; ++it)
      xrow[it] = xb + (size_t)(mp * 256 + (it * 4 + w) * 16 + l15) * D;

    for (int d0 = 0; d0 < D; d0 += 64) {
      __syncthreads();  // previous chunk's Bf reads complete
      // ---- stage B fragments: wave w owns m-tile w, kk = 0,1 ----
#pragma unroll
      for (int kk = 0; kk < 2; ++kk) {
        const float* ap = Ab + (size_t)(d0 + kk * 32 + quad * 8) * MM + mcol;
        const float e0 = ap[0 * MM], e1 = ap[1 * MM], e2 = ap[2 * MM], e3 = ap[3 * MM];
        const float e4 = ap[4 * MM], e5 = ap[5 * MM], e6 = ap[6 * MM], e7 = ap[7 * MM];
        union { unsigned u[4]; short8 s; } bf;
        bf.u[0] = pack2(e0, e1); bf.u[1] = pack2(e2, e3);
        bf.u[2] = pack2(e4, e5); bf.u[3] = pack2(e6, e7);
        Bf[(kk * 4 + w) * 64 + L] = bf.s;   // ds_write_b128, lane-linear
      }
      __syncthreads();
      // ---- compute: A-op = bf16(x_j - x_i); 2 kk x 4 i-tiles x 4 m-tiles ----
#pragma unroll
      for (int kk = 0; kk < 2; ++kk) {
        short8 bfr[4];
#pragma unroll
        for (int mt = 0; mt < 4; ++mt) bfr[mt] = Bf[(kk * 4 + mt) * 64 + L];
        const float* xjp = xjr + d0 + kk * 32 + quad * 8;   // broadcast within quad
        const float4 j0 = *(const float4*)xjp;
        const float4 j1 = *(const float4*)(xjp + 4);
#pragma unroll
        for (int it = 0; it < 4; ++it) {
          const float* xp = xrow[it] + d0 + kk * 32 + quad * 8;
          const float4 v0 = *(const float4*)xp;
          const float4 v1 = *(const float4*)(xp + 4);
          union { unsigned u[4]; short8 s; } af;
          af.u[0] = pack2(j0.x - v0.x, j0.y - v0.y);
          af.u[1] = pack2(j0.z - v0.z, j0.w - v0.w);
          af.u[2] = pack2(j1.x - v1.x, j1.y - v1.y);
          af.u[3] = pack2(j1.z - v1.z, j1.w - v1.w);
#pragma unroll
          for (int mt = 0; mt < 4; ++mt)
            acc[it][mt] = __builtin_amdgcn_mfma_f32_16x16x32_bf16(af.s, bfr[mt], acc[it][mt], 0, 0, 0);
        }
      }
    }

    // ---- epilogue: two 128-i passes (R4 structure); pass p parks tiles 2p,2p+1 ----
#pragma unroll
    for (int p = 0; p < 2; ++p) {
      __syncthreads();  // previous pass's/macro-pass's TsRes reads complete
      // park: i_loc = half*64 + w*16 + quad*4 + r  (covers 0..127)
#pragma unroll
      for (int half = 0; half < 2; ++half)
#pragma unroll
        for (int mt = 0; mt < 4; ++mt)
#pragma unroll
          for (int r = 0; r < 4; ++r)
            TsRes[(half * 64 + w * 16 + quad * 4 + r) * TS_STRIDE + mt * 16 + l15] =
                acc[p * 2 + half][mt][r];
      __syncthreads();

      // ---- Taylor: 2 threads per i, 4 rows each (R4 verbatim, M = Ts directly) ----
      {
        const int i_loc = t >> 1;
        const int r0 = (t & 1) * 4;

        float Mi[8][8];
#pragma unroll
        for (int k = 0; k < 8; ++k)
#pragma unroll
          for (int l = 0; l < 8; ++l)
            Mi[k][l] = TsRes[i_loc * TS_STRIDE + k * 8 + l];
        __syncthreads();  // all Ts reads done; TsRes becomes Res

        float Mp[4][8], res[4][8];
#pragma unroll
        for (int r = 0; r < 4; ++r)
#pragma unroll
          for (int c = 0; c < 8; ++c) {
            const float v = Mi[r0 + r][c];
            Mp[r][c] = v;
            res[r][c] = v + ((r0 + r) == c ? 1.0f : 0.0f);
          }

        const float invn[5] = {0.5f, 1.0f / 3.0f, 0.25f, 0.2f, 1.0f / 6.0f};
#pragma unroll
        for (int n = 0; n < 5; ++n) {
          float np[4][8];
#pragma unroll
          for (int r = 0; r < 4; ++r)
#pragma unroll
            for (int c = 0; c < 8; ++c) {
              float sum = 0.f;
#pragma unroll
              for (int k = 0; k < 8; ++k) sum += Mp[r][k] * Mi[k][c];
              np[r][c] = sum * invn[n];
            }
#pragma unroll
          for (int r = 0; r < 4; ++r)
#pragma unroll
            for (int c = 0; c < 8; ++c) {
              Mp[r][c] = np[r][c];
              res[r][c] += np[r][c];
            }
        }

        // stage result rows in LDS (stride 68 keeps the read pass 2-way-free)
#pragma unroll
        for (int r = 0; r < 4; ++r) {
          f32x4 lo = {res[r][0], res[r][1], res[r][2], res[r][3]};
          f32x4 hi = {res[r][4], res[r][5], res[r][6], res[r][7]};
          *(f32x4*)&TsRes[i_loc * RES_STRIDE + (r0 + r) * 8] = lo;
          *(f32x4*)&TsRes[i_loc * RES_STRIDE + (r0 + r) * 8 + 4] = hi;
        }
      }
      __syncthreads();

      // ---- store: 16 consecutive lanes cover one 256-B (i,j) island ----
      {
        const int part = t & 15;
        const int il0 = t >> 4;  // 0..15
#pragma unroll
        for (int step = 0; step < 8; ++step) {
          const int i_loc = il0 + step * 16;
          const int i = mp * 256 + p * 128 + i_loc;
          const f32x4 v = *(const f32x4*)&TsRes[i_loc * RES_STRIDE + part * 4];
          *(f32x4*)(out + (((size_t)(b * S + i)) * S + j) * MM + part * 4) = v;
        }
      }
    }
  }
}

extern "C" void kernel_launch(void* const* d_in, const int* in_sizes, int n_in,
                              void* d_out, int out_size, void* d_ws, size_t ws_size,
                              hipStream_t stream) {
  const float* x = (const float*)d_in[0];
  const float* A = (const float*)d_in[1];
  float* out = (float*)d_out;
  const int B = in_sizes[0] / (S * D);  // 4
  pt_kernel<<<dim3(B * S), dim3(256), 0, stream>>>(x, A, out);
}